// Round 7
// baseline (109.434 us; speedup 1.0000x reference)
//
#include <hip/hip_runtime.h>
#include <hip/hip_bf16.h>
#include <stdint.h>

// Problem constants
#define BATCH 16
#define IN_CH 64
#define HIN 56
#define WIN_ 56
#define HO 54
#define WO 54
#define P_PER_B (HO*WO)        // 2916
#define P_PAD 2944
#define OUT_CH 256
#define KDIM 576               // 64*3*3
#define NPIX (HIN*WIN_)        // 3136

// gemm tiling
#define NTILES_M 23            // m-tiles of 128 (23*128 = 2944)
#define CHUNKS 8               // m-tile chunks per (b, ngroup)
#define BSLICE_SH 36864        // shorts per n64 B slice (64*576)
#define ABUF_SH 15872          // shorts per A window buf (248 rows * 64)
#define AWIN_GROUPS 31         // 248 rows / 8 rows per 1KB group
#define LDS_BYTES ((BSLICE_SH + 2*ABUF_SH) * 2)   // 137216

typedef __attribute__((ext_vector_type(8))) short short8;
typedef __attribute__((ext_vector_type(4))) float f32x4;

__device__ __forceinline__ unsigned short f2bf(float f) {
    unsigned int u = __float_as_uint(f);
    unsigned int r = (u + 0x7fffu + ((u >> 16) & 1u)) >> 16;   // RNE
    return (unsigned short)r;
}

// ---------------- prep kernels ----------------

// One wave per output channel o: bf16-convert + repack weights into FRAGMENT-LINEAR
// layout wbf2[ng16][tap][ks][quad][nl][8ch] (1KB per fragment, lane-linear 16B)
// so B staging/reads are wave-uniform base + lane*16. Also ||w_o||^2 in fp32.
__global__ void prep_weight(const float* __restrict__ w, short* __restrict__ wbf2,
                            float* __restrict__ c2) {
    int o = blockIdx.x;
    int lane = threadIdx.x;           // 0..63
    int ng = o >> 4, nl = o & 15;
    float s = 0.f;
    #pragma unroll
    for (int j = 0; j < 9; ++j) {     // 576 = 9*64
        int k = j * 64 + lane;        // original k = c*9 + tap
        int c = k / 9, tap = k % 9;
        float v = w[o * KDIM + k];
        s += v * v;
        int ks = c >> 5, qd = (c >> 3) & 3, cl = c & 7;
        ((unsigned short*)wbf2)[((((ng * 9 + tap) * 2 + ks) * 4 + qd) * 16 + nl) * 8 + cl]
            = f2bf(v);
    }
    #pragma unroll
    for (int off = 32; off > 0; off >>= 1) s += __shfl_down(s, off);
    if (lane == 0) c2[o] = s;
}

// NCHW fp32 -> NHWC bf16 transpose (64 pix x 64 ch per block) + fused per-pixel
// channel square-sum s[b, pix].
__global__ __launch_bounds__(256) void transpose_kernel(
    const float* __restrict__ x, short* __restrict__ xT, float* __restrict__ s) {
    __shared__ short lds[64 * 65];
    __shared__ float red[256];
    const int b    = blockIdx.x / 49;
    const int pix0 = (blockIdx.x % 49) * 64;
    const int tid  = threadIdx.x;
    const int quarter = tid >> 6;
    const int pix  = tid & 63;
    const float* xb = x + (size_t)b * IN_CH * NPIX + pix0 + pix;
    float acc = 0.f;
    #pragma unroll
    for (int it = 0; it < 16; ++it) {
        int c = quarter * 16 + it;
        float v = xb[c * NPIX];               // wave reads 256B contiguous
        acc += v * v;
        lds[pix * 65 + c] = (short)f2bf(v);
    }
    red[tid] = acc;
    __syncthreads();
    const int cs = tid & 63;
    short* xTb = xT + ((size_t)b * NPIX + pix0) * 64;
    #pragma unroll
    for (int it = 0; it < 16; ++it) {
        int pixs = quarter * 16 + it;
        xTb[(size_t)pixs * 64 + cs] = lds[pixs * 65 + cs];  // wave writes 128B contiguous
    }
    if (tid < 64)
        s[b * NPIX + pix0 + tid] = red[tid] + red[64 + tid] + red[128 + tid] + red[192 + tid];
}

// w2[b*P_PAD + p] = 3x3 window sum of s  (= ||win_p||^2, fp32)
__global__ void w2_kernel(const float* __restrict__ s, float* __restrict__ w2) {
    int t = blockIdx.x * 256 + threadIdx.x;
    if (t >= BATCH * P_PER_B) return;
    int b = t / P_PER_B, p = t % P_PER_B;
    int oh = p / WO, ow = p % WO;
    const float* sp = s + b * NPIX + oh * WIN_ + ow;
    float acc = 0.f;
    #pragma unroll
    for (int kh = 0; kh < 3; ++kh)
        #pragma unroll
        for (int kw = 0; kw < 3; ++kw)
            acc += sp[kh * WIN_ + kw];
    w2[b * P_PAD + p] = acc;
}

// ---------------- fused im2col GEMM + RBF epilogue ----------------
// B-RESIDENT design: block = (batch, n64-group, m-chunk). Stages its 72 KB
// fragment-linear B slice into LDS ONCE, then loops over ~3 m-tiles of 128
// positions. Per tile, the contiguous 31.7 KB A-window (248 xT rows, covers
// all 9 taps) is staged into a double buffer via global_load_lds with
// XOR-swizzled per-lane SOURCE addresses (round-2-verified conflict-free
// fragment reads). One barrier per tile; the A-prefetch for tile i+1 is
// issued before ~3000 cycles of ds_read+MFMA, so its drain at the barrier
// is free. B traffic: 512 x 72 KB = 38 MB (was 212 MB).

#define AS1(p) ((const __attribute__((address_space(1))) void*)(p))
#define AS3(p) ((__attribute__((address_space(3))) void*)(p))

__global__ __launch_bounds__(256, 1) void gemm_rbf(
    const short* __restrict__ xT, const short* __restrict__ wbf2,
    const float* __restrict__ w2, const float* __restrict__ c2,
    float* __restrict__ out) {
    constexpr int dtab[9] = {0, 1, 2, 56, 57, 58, 112, 113, 114};  // kh*56+kw
    extern __shared__ __align__(16) short lds[];
    short* ldsB = lds;                         // 72 KB fragment-linear B

    const int chunk = blockIdx.x;              // 0..7  -> m-tiles chunk, chunk+8, ...
    const int ng    = blockIdx.y;              // 0..3  n64 channel group
    const int b     = blockIdx.z;              // 0..15 batch

    const int tid  = threadIdx.x;
    const int wave = tid >> 6;
    const int lane = tid & 63;
    const int r16  = lane & 15;
    const int quad = lane >> 4;
    const int srow = lane >> 3;                // staging row-in-group
    const int soff = srow * 128 + ((lane & 7) ^ srow) * 16;  // swizzled src offset

    const char* xTb = (const char*)(xT + (size_t)b * NPIX * 64);

    // ---- stage B once: 72 groups of 1 KB ----
    const char* bsrc = (const char*)(wbf2 + (size_t)ng * BSLICE_SH) + lane * 16;
    for (int g = wave; g < 72; g += 4)
        __builtin_amdgcn_global_load_lds(AS1(bsrc + g * 1024), AS3(ldsB + g * 512), 16, 0, 0);

    // ---- stage A window for first tile into buf 0 ----
    {
        int p0 = chunk * 128;
        int q0 = p0 + 2 * (p0 / WO);
        const char* wb = xTb + (size_t)q0 * 128;
        for (int g = wave; g < AWIN_GROUPS; g += 4)
            __builtin_amdgcn_global_load_lds(AS1(wb + g * 1024 + soff),
                                             AS3(lds + BSLICE_SH + g * 512), 16, 0, 0);
    }
    __syncthreads();

    int i = 0;
    for (int t = chunk; t < NTILES_M; t += CHUNKS, ++i) {
        const int p0 = t * 128;
        const int q0 = p0 + 2 * (p0 / WO);
        const short* A = lds + BSLICE_SH + (i & 1) * ABUF_SH;

        // prefetch next tile's window (drained at end-of-iteration barrier)
        if (t + CHUNKS < NTILES_M) {
            int p0n = (t + CHUNKS) * 128;
            int q0n = p0n + 2 * (p0n / WO);
            const char* wb = xTb + (size_t)q0n * 128;
            short* dst = lds + BSLICE_SH + ((i + 1) & 1) * ABUF_SH;
            for (int g = wave; g < AWIN_GROUPS; g += 4)
                __builtin_amdgcn_global_load_lds(AS1(wb + g * 1024 + soff),
                                                 AS3(dst + g * 512), 16, 0, 0);
        }

        // per-lane A rows for this tile (wave covers m32)
        int qr[2];
        #pragma unroll
        for (int ms = 0; ms < 2; ++ms) {
            int p = p0 + wave * 32 + ms * 16 + r16;
            if (p > P_PER_B - 1) p = P_PER_B - 1;
            qr[ms] = (p + 2 * (p / WO)) - q0;
        }

        f32x4 acc[2][4];
        #pragma unroll
        for (int ms = 0; ms < 2; ++ms)
            #pragma unroll
            for (int ns = 0; ns < 4; ++ns)
                acc[ms][ns] = (f32x4){0.f, 0.f, 0.f, 0.f};

        #pragma unroll
        for (int tap = 0; tap < 9; ++tap) {
            short8 af[2][2], bf[4][2];
            #pragma unroll
            for (int ms = 0; ms < 2; ++ms) {
                int row = qr[ms] + dtab[tap];
                const short* aRow = A + row * 64;
                int key = row & 7;
                #pragma unroll
                for (int ks = 0; ks < 2; ++ks)
                    af[ms][ks] = *(const short8*)(aRow + (((ks * 4 + quad) ^ key) * 8));
            }
            #pragma unroll
            for (int ns = 0; ns < 4; ++ns)
                #pragma unroll
                for (int ks = 0; ks < 2; ++ks)
                    bf[ns][ks] = *(const short8*)(ldsB + ns * 9216 + lane * 8
                                                  + (tap * 2 + ks) * 512);
            #pragma unroll
            for (int ks = 0; ks < 2; ++ks)
                #pragma unroll
                for (int ms = 0; ms < 2; ++ms)
                    #pragma unroll
                    for (int ns = 0; ns < 4; ++ns)
                        acc[ms][ns] = __builtin_amdgcn_mfma_f32_16x16x32_bf16(
                            af[ms][ks], bf[ns][ks], acc[ms][ns], 0, 0, 0);
        }

        // Epilogue: D layout n = lane&15, m = quad*4 + reg -> float4 per (ms,ns)
        #pragma unroll
        for (int ms = 0; ms < 2; ++ms) {
            int p = p0 + wave * 32 + ms * 16 + quad * 4;
            if (p < P_PER_B) {
                f32x4 w2v = *(const f32x4*)(w2 + b * P_PAD + p);
                bool full = (p + 3 < P_PER_B);
                #pragma unroll
                for (int ns = 0; ns < 4; ++ns) {
                    int o = ng * 64 + ns * 16 + r16;
                    float c2o = c2[o];
                    f32x4 v;
                    #pragma unroll
                    for (int r = 0; r < 4; ++r) {
                        float d2 = w2v[r] + c2o - 2.0f * acc[ms][ns][r];
                        d2 = fmaxf(d2, 1e-12f);
                        v[r] = __expf(-0.125f * d2);
                    }
                    float* outp = out + ((size_t)(b * OUT_CH + o)) * P_PER_B + p;
                    if (full) {
                        *(f32x4*)outp = v;
                    } else {
                        #pragma unroll
                        for (int r = 0; r < 4; ++r)
                            if (p + r < P_PER_B) outp[r] = v[r];
                    }
                }
            }
        }
        __syncthreads();   // drains prefetch; protects buf reuse
    }
}

// ---------------- launch ----------------

extern "C" void kernel_launch(void* const* d_in, const int* in_sizes, int n_in,
                              void* d_out, int out_size, void* d_ws, size_t ws_size,
                              hipStream_t stream) {
    const float* x = (const float*)d_in[0];    // [16,64,56,56]
    const float* w = (const float*)d_in[1];    // [256,576]
    float* out = (float*)d_out;                // [16,256,54,54]

    char* ws = (char*)d_ws;
    const size_t wbf_bytes = (size_t)OUT_CH * KDIM * 2;            // 294,912
    const size_t c2_bytes  = 1024;
    const size_t w2_bytes  = (size_t)BATCH * P_PAD * 4;            // 188,416
    const size_t s_bytes   = (size_t)BATCH * NPIX * 4;             // 200,704
    short* wbf2 = (short*)ws;
    float* c2  = (float*)(ws + wbf_bytes);
    float* w2  = (float*)(ws + wbf_bytes + c2_bytes);
    float* s   = (float*)(ws + wbf_bytes + c2_bytes + w2_bytes);
    short* xT  = (short*)(ws + wbf_bytes + c2_bytes + w2_bytes + s_bytes);  // 6.4 MB
    // gemm over-reads <= 4.5 KB past xT's end (tail-tile windows) — inside d_ws.

    // allow 137 KB dynamic LDS (gfx950 has 160 KB/WG)
    (void)hipFuncSetAttribute((const void*)gemm_rbf,
                              hipFuncAttributeMaxDynamicSharedMemorySize, LDS_BYTES);

    hipLaunchKernelGGL(prep_weight, dim3(OUT_CH), dim3(64), 0, stream, w, wbf2, c2);
    hipLaunchKernelGGL(transpose_kernel, dim3(16 * 49), dim3(256), 0, stream, x, xT, s);
    hipLaunchKernelGGL(w2_kernel, dim3((BATCH * P_PER_B + 255) / 256), dim3(256), 0, stream, s, w2);
    hipLaunchKernelGGL(gemm_rbf, dim3(CHUNKS, 4, BATCH), dim3(256), LDS_BYTES, stream,
                       xT, wbf2, w2, c2, out);
}